// Round 5
// baseline (378.054 us; speedup 1.0000x reference)
//
#include <hip/hip_runtime.h>
#include <math.h>

// ConvKAN3D: 3x [conv3d(3x3x3,pad1) -> cubic KAN spline + SiLU -> BN(eval) -> maxpool 2x2x2]
// then global mean pool + fc1/relu/fc2.
// r15: r14 + RACE FIX. r14's post-timing divergence was a scratch collision in the
// CSPLIT reduction: index omitted the spatial wave-tile id sw_, so with NSW=2 the
// two spatial tiles' cg>0 waves wrote the SAME scratch cells (bug introduced in r12;
// r12's absmax 9.77e-4 was this race; r13's NSW=1 masked it). Fixed by indexing
// scratch with ((idx*(CSPLIT-1)+(cg-1))*NSW + sw_)*64 + lane.
// r14 design kept (unmeasured): padded tensors (x/h1/h2 +1 halo, zeroed) make every
// tile w-origin 16B-aligned -> woff=0:
//   - r[] reads become even 8B ds_read_b64 (conflict-free; r12 counters showed the
//     old odd-address pattern wasted 13.6% of all CU cycles on bank conflicts)
//   - row = 18 cols -> 5 chunks (PITCH 20): LDS/buf 4.8KB, 5 DMA (vmcnt(5)),
//     tail DMA exec-masked to 44 lanes
//   - no validity masks / zbuf
//   - L2 LDS 39.1KB -> 4 blocks/CU = 16 waves/CU, grid 1024 = 1 clean round;
//     L1 19.9KB -> 8 blocks/CU.
// Barrier-free K-loop kept (r11): private per-wave dbuf tiles, global_load_lds w16,
// counted s_waitcnt vmcnt(5).
// HARD CONSTRAINTS (measured): G<=4 with r[64] (G=8 spills: r8 WRITE 964MB);
// launch_bounds stays (TPB,2) (r6); never split cin via global atomics (r5);
// CSPLIT scratch MUST be indexed by (cg, sw_) jointly (r14 replay race).

#define GLOBAL_AS __attribute__((address_space(1)))
#define LDS_AS    __attribute__((address_space(3)))

static __device__ __forceinline__ void async_ld16(const float* g, float* l) {
    __builtin_amdgcn_global_load_lds((const GLOBAL_AS void*)g, (LDS_AS void*)l,
                                     16, 0, 0);
}

// blocks 0..40: pack conv weights [C][CIN][27] -> [C*CIN][28] (float4 x7, tail 0)
// blocks 41.. : build x_pad [2][66][66][68] from x [2][1][64][64][64] (pads = 0)
__global__ __launch_bounds__(256) void prep_kernel(
    const float* __restrict__ x,
    const float* __restrict__ w1, const float* __restrict__ w2,
    const float* __restrict__ w3,
    float* __restrict__ xp,
    float* __restrict__ o1, float* __restrict__ o2, float* __restrict__ o3)
{
    const int b = blockIdx.x;
    if (b < 41) {
        const int i = b * 256 + threadIdx.x;   // (c,ci) pair id
        const float* src;
        float* dst;
        if (i < 32)         { src = w1 + i * 27;              dst = o1 + i * 28; }
        else if (i < 2080)  { const int j = i - 32;    src = w2 + j * 27; dst = o2 + j * 28; }
        else if (i < 10272) { const int j = i - 2080;  src = w3 + j * 27; dst = o3 + j * 28; }
        else return;
#pragma unroll
        for (int t = 0; t < 27; t++) dst[t] = src[t];
        dst[27] = 0.0f;
    } else {
        const int idx = (b - 41) * 256 + threadIdx.x;
        if (idx >= 2 * 66 * 66 * 68) return;
        const int wp = idx % 68;
        int t = idx / 68;
        const int hp = t % 66; t /= 66;
        const int dp = t % 66;
        const int nn = t / 66;
        float v = 0.0f;
        if (dp >= 1 && dp <= 64 && hp >= 1 && hp <= 64 && wp >= 1 && wp <= 64)
            v = x[(((size_t)nn * 64 + dp - 1) * 64 + hp - 1) * 64 + wp - 1];
        xp[idx] = v;
    }
}

template <int TPB_, int CIN, int CSPLIT, int G,
          int WDT, int WHT, int WWT, int BD, int BH, int BW>
__global__ __launch_bounds__(TPB_, 2) void spline_block_kernel(
    const float* __restrict__ x,    // padded input [N, CIN, DP, IHP, IWP]
    const float4* __restrict__ wpk, // [Cout*CIN][7] packed conv weights
    const float* __restrict__ cb,   // [Cout]
    const float* __restrict__ knots,// [10]
    const float* __restrict__ sw,   // [Cout, 10]
    const float* __restrict__ w1,
    const float* __restrict__ w2,
    const float* __restrict__ g,
    const float* __restrict__ beta,
    float* __restrict__ out,        // [N, Cout, ODP, OHP, OWP] (+OPAD offset)
    int N, int Cout,
    int ICH, int IHP, int IWP,      // input per-channel dwords, padded H rows, padded W pitch
    int ODP, int OHP, int OWP, int OPAD,
    int ntiles, int nthw, int ntw)
{
    constexpr int NSW    = BD * BH * BW;       // spatial wave-tiles per block
    constexpr int NW     = TPB_ / 64;          // waves per block
    constexpr int CPG    = CIN / CSPLIT;       // cins per cin-group
    constexpr int ID     = 2 * WDT + 2;        // input planes (d) per wave tile
    constexpr int IH     = 2 * WHT + 2;        // input rows (h) per wave tile
    constexpr int CHK    = 5;                  // 16B chunks per row (18 cols used)
    constexpr int PITCH  = CHK * 4;            // 20 dwords per row
    constexpr int ROWS   = ID * IH;
    constexpr int CHUNKS = ROWS * CHK;         // 300
    constexpr int PHYS   = ROWS * PITCH;       // 1200 dwords per wave buffer
    constexpr int NCH    = (CHUNKS + 63) / 64; // 5 DMA issues per cin per lane
    constexpr int TAIL   = CHUNKS & 63;        // 44 active lanes in last issue
    constexpr int BUFS   = (CPG > 1) ? 2 : 1;
    static_assert(NW == NSW * CSPLIT, "waves = spatial-tiles x cin-split");
    static_assert(WDT * WHT * WWT == 64, "one wave per spatial tile");
    static_assert(WDT == 2 && WHT == 4 && WWT == 8, "tile geometry fixed");
    static_assert(CIN % CSPLIT == 0, "cin divisible");
    static_assert(G == 4, "acc layout assumes G==4");
    static_assert(NCH == 5, "s_waitcnt vmcnt(5) literal assumes 5 issues/cin");
    static_assert(CSPLIT == 1 ||
                  (CSPLIT - 1) * NSW * 64 * G * 8 <= NW * BUFS * PHYS,
                  "reduction scratch fits in tile");

    __shared__ __align__(16) float tile[NW][BUFS][PHYS];
    __shared__ float4 stbl[G * 11];            // spline prefix coeffs {A,3B,3C,D}

    const int groups = Cout / G;
    const int tid  = threadIdx.x;
    const int wv   = tid >> 6;                 // wave id
    const int lane = tid & 63;
    const int sw_  = wv % NSW;                 // spatial wave-tile id
    const int cg   = wv / NSW;                 // cin-group id

    const int bx      = blockIdx.x;
    const int tile_id = bx % ntiles;
    const int t1      = bx / ntiles;
    const int grp     = t1 % groups;
    const int n       = t1 / groups;
    const int c0      = grp * G;
    const int cinbase = cg * CPG;

    const int td  = tile_id / nthw;
    const int rem = tile_id % nthw;
    const int th_ = rem / ntw;
    const int tw_ = rem % ntw;

    // spline prefix-coeff table (covered by the single initial barrier)
    for (int i = tid; i < G * 11; i += TPB_) {
        const int gg  = i / 11;
        const int cnt = i % 11;
        const int c   = c0 + gg;
        float A = 0.f, B3 = 0.f, C3 = 0.f, Dd = 0.f;
        for (int j = 0; j < cnt; j++) {
            const float s = sw[c * 10 + j];
            const float k = knots[j];
            A  += s;
            B3 += 3.0f * s * k;
            C3 += 3.0f * s * k * k;
            Dd += s * k * k * k;
        }
        stbl[i] = make_float4(A, B3, C3, Dd);
    }

    // wave spatial origin (pooled coords)
    const int swd = sw_ / (BH * BW);
    const int r2  = sw_ % (BH * BW);
    const int swh = r2 / BW;
    const int sww = r2 % BW;
    const int pd0 = td  * (BD * WDT) + swd * WDT;
    const int ph0 = th_ * (BH * WHT) + swh * WHT;
    const int pw0 = tw_ * (BW * WWT) + sww * WWT;

    const int pwl = lane % WWT;
    const int phl = (lane / WWT) % WHT;
    const int pdl = lane / (WWT * WHT);

    // per-chunk input offsets (padded coords: dp = 2*pd0+dz, hp = 2*ph0+hy,
    // w-base = 2*pw0 which is 16B-aligned). All chunks valid (pads are zero).
    int off[NCH];
#pragma unroll
    for (int k = 0; k < NCH; k++) {
        const int chunk = lane + 64 * k;
        const int row = chunk / CHK, cs = chunk - row * CHK;
        const int dz = row / IH, hy = row - dz * IH;
        off[k] = ((2 * pd0 + dz) * IHP + (2 * ph0 + hy)) * IWP +
                 2 * pw0 + cs * 4;
    }

    float acc[G][8];
#pragma unroll
    for (int gg = 0; gg < G; gg++)
#pragma unroll
        for (int i = 0; i < 8; i++) acc[gg][i] = 0.0f;

    __syncthreads();   // stbl visible; vmcnt drained (clean slate)

    auto stage = [&](int ci, int buf) {
        const float* xc = x + ((size_t)n * CIN + ci) * ICH;
        float* dst = &tile[wv][buf][0];
#pragma unroll
        for (int k = 0; k < NCH; k++) {
            const int chunk = lane + 64 * k;
            if ((k + 1) * 64 <= CHUNKS || lane < TAIL)
                async_ld16(xc + off[k], dst + chunk * 4);
        }
    };

    // prologue: each wave stages its first cin into its buf 0
    stage(cinbase, 0);

#pragma unroll 1
    for (int s = 0; s < CPG; s++) {
        const int cur = s & (BUFS - 1);
        if (s + 1 < CPG) {
            stage(cinbase + s + 1, cur ^ 1);   // 5 DMA issues, stay in flight
            asm volatile("s_waitcnt vmcnt(5)" ::: "memory");  // cin s landed
        } else {
            asm volatile("s_waitcnt vmcnt(0)" ::: "memory");
        }

        const int ci = cinbase + s;
        const float* tb = &tile[wv][cur][0];
        float r[64];
#pragma unroll
        for (int dz = 0; dz < 4; dz++)
#pragma unroll
        for (int dy = 0; dy < 4; dy++) {
            const int rb = ((2 * pdl + dz) * IH + (2 * phl + dy)) * PITCH +
                           2 * pwl;                 // even -> ds_read_b64 pair
            const float2 a = *reinterpret_cast<const float2*>(&tb[rb]);
            const float2 b = *reinterpret_cast<const float2*>(&tb[rb + 2]);
            const int base = (dz * 4 + dy) * 4;
            r[base + 0] = a.x; r[base + 1] = a.y;
            r[base + 2] = b.x; r[base + 3] = b.y;
        }

#pragma unroll
        for (int gg = 0; gg < G; gg++) {
            const float4* wp = wpk + ((size_t)(c0 + gg) * CIN + ci) * 7;
            float4 q[7];
#pragma unroll
            for (int ch = 0; ch < 7; ch++) q[ch] = wp[ch];
#pragma unroll
            for (int ch = 0; ch < 7; ch++) {
#pragma unroll
                for (int j = 0; j < 4; j++) {
                    const int tap = ch * 4 + j;
                    if (tap < 27) {
                        const float wvj = (j == 0) ? q[ch].x : (j == 1) ? q[ch].y
                                        : (j == 2) ? q[ch].z : q[ch].w;
                        const int kd = tap / 9, kh = (tap % 9) / 3, kw = tap % 3;
#pragma unroll
                        for (int od = 0; od < 2; od++)
#pragma unroll
                        for (int oh = 0; oh < 2; oh++)
#pragma unroll
                        for (int ow = 0; ow < 2; ow++)
                            acc[gg][(od * 2 + oh) * 2 + ow] =
                                fmaf(wvj,
                                     r[((od + kd) * 4 + (oh + kh)) * 4 + (ow + kw)],
                                     acc[gg][(od * 2 + oh) * 2 + ow]);
                    }
                }
            }
        }
    }

    // combine partial accumulators across cin-groups (scratch aliases tile).
    // NOTE: scratch index MUST include sw_ (per-spatial-tile slot) — omitting it
    // made NSW=2 geometries race (r14 post-timing divergence).
    float* af = &acc[0][0];
    if (CSPLIT > 1) {
        __syncthreads();                        // all waves done with their tiles
        float* scratch = &tile[0][0][0];
        if (cg > 0) {
#pragma unroll
            for (int idx = 0; idx < G * 8; idx++)
                scratch[((idx * (CSPLIT - 1) + (cg - 1)) * NSW + sw_) * 64 + lane]
                    = af[idx];
        }
        __syncthreads();
        if (cg == 0) {
#pragma unroll
            for (int idx = 0; idx < G * 8; idx++) {
                float s2 = af[idx];
                for (int j = 0; j < CSPLIT - 1; j++)
                    s2 += scratch[((idx * (CSPLIT - 1) + j) * NSW + sw_) * 64 + lane];
                af[idx] = s2;
            }
        }
    }

    // epilogue (cin-group 0): bias + spline (prefix-Horner) + SiLU + BN + maxpool
    if (cg == 0) {
        const int pdg = pd0 + pdl, phg = ph0 + phl, pwg = pw0 + pwl;
#pragma unroll
        for (int gg = 0; gg < G; gg++) {
            const int c = c0 + gg;
            const float bias = cb[c];
            const float W1 = w1[c], W2 = w2[c];
            const float scale = g[c] * rsqrtf(1.0f + 1e-5f);
            const float bb = beta[c];

            float m = -INFINITY;
#pragma unroll
            for (int i = 0; i < 8; i++) {
                const float y = acc[gg][i] + bias;
                int idx = (int)floorf((y + 1.0f) * 4.5f) + 1;
                idx = min(max(idx, 0), 10);
                const float4 cf = stbl[gg * 11 + idx];
                const float sp = ((cf.x * y - cf.y) * y + cf.z) * y - cf.w;
                const float silu = y / (1.0f + __expf(-y));
                const float o = fmaf(W1 * sp + W2 * silu, scale, bb);
                m = fmaxf(m, o);
            }
            out[(((size_t)(n * Cout + c) * ODP + pdg + OPAD) * OHP +
                 phg + OPAD) * OWP + pwg + OPAD] = m;
        }
    }
}

// Fused head: global mean pool (256 rows of 512) + fc1/relu + fc2. One block.
__global__ __launch_bounds__(256) void head_kernel(
    const float* __restrict__ h,    // [2*128][512] = h3
    const float* __restrict__ fw1, const float* __restrict__ fb1,
    const float* __restrict__ fw2, const float* __restrict__ fb2,
    float* __restrict__ out)        // [2][2]
{
    __shared__ float pooled[256];
    __shared__ float hbuf[2][256];
    const int tid = threadIdx.x, w = tid >> 6, lane = tid & 63;
    for (int p = w; p < 256; p += 4) {
        const float* row = h + (size_t)p * 512;
        float s = 0.0f;
#pragma unroll
        for (int i = 0; i < 8; i++) s += row[lane + 64 * i];
#pragma unroll
        for (int o = 32; o > 0; o >>= 1) s += __shfl_down(s, o, 64);
        if (lane == 0) pooled[p] = s * (1.0f / 512.0f);
    }
    __syncthreads();
    const int j = tid;
#pragma unroll
    for (int nn = 0; nn < 2; nn++) {
        float s = fb1[j];
        for (int k = 0; k < 128; k++)
            s = fmaf(pooled[nn * 128 + k], fw1[j * 128 + k], s);
        hbuf[nn][j] = fmaxf(s, 0.0f);
    }
    __syncthreads();
    const int wid = j >> 6, l2 = j & 63;
    const int nn = wid >> 1, oo = wid & 1;
    float s = 0.0f;
    for (int k = l2; k < 256; k += 64) s += hbuf[nn][k] * fw2[oo * 256 + k];
#pragma unroll
    for (int o = 32; o > 0; o >>= 1) s += __shfl_down(s, o, 64);
    if (l2 == 0) out[nn * 2 + oo] = s + fb2[oo];
}

extern "C" void kernel_launch(void* const* d_in, const int* in_sizes, int n_in,
                              void* d_out, int out_size, void* d_ws, size_t ws_size,
                              hipStream_t stream) {
    const float* x      = (const float*)d_in[0];
    const float* c1_w   = (const float*)d_in[1];
    const float* c1_b   = (const float*)d_in[2];
    const float* c1_kn  = (const float*)d_in[3];
    const float* c1_sw  = (const float*)d_in[4];
    const float* c1_w1  = (const float*)d_in[5];
    const float* c1_w2  = (const float*)d_in[6];
    const float* bn1_g  = (const float*)d_in[7];
    const float* bn1_b  = (const float*)d_in[8];
    const float* c2_w   = (const float*)d_in[9];
    const float* c2_b   = (const float*)d_in[10];
    const float* c2_kn  = (const float*)d_in[11];
    const float* c2_sw  = (const float*)d_in[12];
    const float* c2_w1  = (const float*)d_in[13];
    const float* c2_w2  = (const float*)d_in[14];
    const float* bn2_g  = (const float*)d_in[15];
    const float* bn2_b  = (const float*)d_in[16];
    const float* c3_w   = (const float*)d_in[17];
    const float* c3_b   = (const float*)d_in[18];
    const float* c3_kn  = (const float*)d_in[19];
    const float* c3_sw  = (const float*)d_in[20];
    const float* c3_w1  = (const float*)d_in[21];
    const float* c3_w2  = (const float*)d_in[22];
    const float* bn3_g  = (const float*)d_in[23];
    const float* bn3_b  = (const float*)d_in[24];
    const float* fc1_w  = (const float*)d_in[25];
    const float* fc1_b  = (const float*)d_in[26];
    const float* fc2_w  = (const float*)d_in[27];
    const float* fc2_b  = (const float*)d_in[28];

    float* ws = (float*)d_ws;
    // padded layouts (all pads zero):
    // x_pad  [2][66][66][68]   = 592,416 dw
    // h1_pad [2][32][34][34][36] = 2,663,424 dw
    // h2_pad [2][64][18][18][20] =   829,440 dw
    // h3     [2][128][8][8][8]   =   131,072 dw
    float* x_pad  = ws;
    float* h1_pad = x_pad + 592416;
    float* h2_pad = h1_pad + 2663424;
    float* h3     = h2_pad + 829440;
    float* wp1    = h3 + 131072;         // 32*1*28   =     896 dw
    float* wp2    = wp1 + 896;           // 64*32*28  =  57,344 dw
    float* wp3    = wp2 + 57344;         // 128*64*28 = 229,376 dw

    // zero the padded inter-layer buffers (pads must be 0; interiors overwritten)
    hipMemsetAsync(h1_pad, 0, 2663424 * sizeof(float), stream);
    hipMemsetAsync(h2_pad, 0, 829440 * sizeof(float), stream);

    // pack conv weights + build x_pad
    prep_kernel<<<dim3(41 + 2315), dim3(256), 0, stream>>>(
        x, c1_w, c2_w, c3_w, x_pad, wp1, wp2, wp3);

    // All layers: wave tile 2x4x8, padded inputs: ID=6, IH=10, PITCH=20,
    // 5 DMA issues/cin (vmcnt(5)), aligned ds_read_b64, conflict-free.
    // L1: (2,1,66p)->(2,32,34p). 4 spatial waves (1x1x4). LDS 19.9KB -> 8
    // blocks/CU. ntiles = 16d x 8h x 1 = 128, grid = 2*8*128 = 2048.
    spline_block_kernel<256, 1, 1, 4, 2, 4, 8, 1, 1, 4>
        <<<dim3(2048), dim3(256), 0, stream>>>(
        x_pad, (const float4*)wp1, c1_b, c1_kn, c1_sw, c1_w1, c1_w2, bn1_g, bn1_b,
        h1_pad, 2, 32, 296208, 66, 68, 34, 34, 36, 1, 128, 8, 1);
    // L2: (2,32,34p)->(2,64,18p). 2 spatial x CSPLIT=2. LDS 39.1KB -> 4
    // blocks/CU = 16 waves/CU; ntiles = 8d x 4h x 1 = 32, grid = 2*16*32 = 1024
    // = exactly 4 blocks/CU -> one clean round.
    spline_block_kernel<256, 32, 2, 4, 2, 4, 8, 1, 1, 2>
        <<<dim3(1024), dim3(256), 0, stream>>>(
        h1_pad, (const float4*)wp2, c2_b, c2_kn, c2_sw, c2_w1, c2_w2, bn2_g, bn2_b,
        h2_pad, 2, 64, 41616, 34, 36, 18, 18, 20, 1, 32, 4, 1);
    // L3: (2,64,18p)->(2,128,8). CSPLIT=4. ntiles = 4d x 2h x 1 = 8,
    // grid = 2*32*8 = 512 (grid-limited at 8 waves/CU).
    spline_block_kernel<256, 64, 4, 4, 2, 4, 8, 1, 1, 1>
        <<<dim3(512), dim3(256), 0, stream>>>(
        h2_pad, (const float4*)wp3, c3_b, c3_kn, c3_sw, c3_w1, c3_w2, bn3_g, bn3_b,
        h3, 2, 128, 6480, 18, 20, 8, 8, 8, 0, 8, 2, 1);
    // fused head (mean pool + fc1 + fc2)
    head_kernel<<<dim3(1), dim3(256), 0, stream>>>(h3, fc1_w, fc1_b, fc2_w, fc2_b,
                                                   (float*)d_out);
}

// Round 6
// 377.444 us; speedup vs baseline: 1.0016x; 1.0016x over previous
//
#include <hip/hip_runtime.h>
#include <math.h>

// ConvKAN3D: 3x [conv3d(3x3x3,pad1) -> cubic KAN spline + SiLU -> BN(eval) -> maxpool 2x2x2]
// then global mean pool + fc1/relu/fc2.
// r16: revert to r12 base (best measured: L1 33.6 / L2 126 / L3 67.2), then:
//  (1) SCALAR WEIGHTS: readfirstlane(cinbase) -> uniform address -> s_load (SMEM,
//      lgkmcnt). Mechanism: r12's per-lane weight loads shared the in-order vmcnt
//      queue with the prefetch DMAs -- consuming gg0's weights forced the fresh
//      next-tile DMAs to retire, serializing L2 latency into EVERY step. Scalar
//      weights use a separate counter; also frees 28 VGPRs.
//  (2) L1 CGO=8: CIN=1 made one 864-FMA step amortize a whole prologue+stage
//      (33.6us vs 5.8us FMA floor). Now stage tile + load r[64] ONCE, loop 8
//      cout-groups (weights+FMA+epilogue) over the same registers. grid=256.
//  (3) CSPLIT-reduction race fix (scratch indexed by (cg, sw_) jointly -- r14's
//      replay divergence) + fused head kernel (removes the 12us fc bubble).
// Measured-dead-ends (do not retry): padding/alignment of LDS reads (r15: conflict
// counter is structural, unchanged; dur worse), TPB=128 blocks (r13), G=8 with
// r[64] (r8 spill), cin-split via global atomics (r5). launch_bounds stays (TPB,2).

#define GLOBAL_AS __attribute__((address_space(1)))
#define LDS_AS    __attribute__((address_space(3)))

static __device__ __forceinline__ void async_ld16(const float* g, float* l) {
    __builtin_amdgcn_global_load_lds((const GLOBAL_AS void*)g, (LDS_AS void*)l,
                                     16, 0, 0);
}

// Pack [C][CIN][27] conv weights -> [C*CIN][28] (16B-aligned float4 x 7, tail 0)
__global__ __launch_bounds__(256) void repack_kernel(
    const float* __restrict__ w1, const float* __restrict__ w2,
    const float* __restrict__ w3,
    float* __restrict__ o1, float* __restrict__ o2, float* __restrict__ o3)
{
    const int i = blockIdx.x * 256 + threadIdx.x;   // (c,ci) pair id
    const float* src;
    float* dst;
    if (i < 32)            { src = w1 + i * 27;           dst = o1 + i * 28; }
    else if (i < 2080)     { const int j = i - 32;   src = w2 + j * 27; dst = o2 + j * 28; }
    else if (i < 10272)    { const int j = i - 2080; src = w3 + j * 27; dst = o3 + j * 28; }
    else return;
#pragma unroll
    for (int t = 0; t < 27; t++) dst[t] = src[t];
    dst[27] = 0.0f;
}

template <int TPB_, int CIN, int CSPLIT, int G, int CGO,
          int WDT, int WHT, int WWT, int BD, int BH, int BW>
__global__ __launch_bounds__(TPB_, 2) void spline_block_kernel(
    const float* __restrict__ x,    // [N, CIN, D, H, W]
    const float4* __restrict__ wpk, // [Cout*CIN][7] packed conv weights
    const float* __restrict__ cb,   // [Cout]
    const float* __restrict__ knots,// [10]
    const float* __restrict__ sw,   // [Cout, 10]
    const float* __restrict__ w1,
    const float* __restrict__ w2,
    const float* __restrict__ g,
    const float* __restrict__ beta,
    const float* __restrict__ zbuf, // >=64B of zeros (16B aligned)
    float* __restrict__ out,        // [N, Cout, D/2, H/2, W/2]
    int N, int Cout, int D, int H, int W,
    int ntiles, int nthw, int ntw)
{
    constexpr int GTOT   = G * CGO;            // couts per block
    constexpr int NSW    = BD * BH * BW;       // spatial wave-tiles per block
    constexpr int NW     = TPB_ / 64;          // waves per block
    constexpr int CPG    = CIN / CSPLIT;       // cins per cin-group
    constexpr int ID     = 2 * WDT + 2;        // input planes (d) per wave tile
    constexpr int IH     = 2 * WHT + 2;        // input rows (h) per wave tile
    constexpr int CHK    = (WWT + 4) / 2;      // 16B chunks per input row
    constexpr int PITCH  = CHK * 4;            // dwords per row
    constexpr int ROWS   = ID * IH;
    constexpr int CHUNKS = ROWS * CHK;
    constexpr int PHYS   = CHUNKS * 4;         // dwords per wave buffer
    constexpr int NCH    = (CHUNKS + 63) / 64; // DMA issues per cin per lane
    constexpr int BUFS   = (CPG > 1) ? 2 : 1;
    static_assert(NW == NSW * CSPLIT, "waves = spatial-tiles x cin-split");
    static_assert(WDT * WHT * WWT == 64, "one wave per spatial tile");
    static_assert(CIN % CSPLIT == 0, "cin divisible");
    static_assert(G == 4, "acc layout assumes G==4");
    static_assert(CGO == 1 || (CSPLIT == 1 && CIN == 1),
                  "multi-cout-group only for the CIN=1 single-step layer");
    static_assert(NCH <= 32, "mask fits u32");
    static_assert(NCH == 6, "s_waitcnt vmcnt(6) literal assumes 6 issues/cin");
    static_assert(CSPLIT == 1 ||
                  (CSPLIT - 1) * NSW * 64 * G * 8 <= NW * BUFS * PHYS,
                  "reduction scratch fits in tile");

    __shared__ __align__(16) float tile[NW][BUFS][PHYS];
    __shared__ float4 stbl[GTOT * 11];         // spline prefix coeffs {A,3B,3C,D}

    const int PD = D >> 1, PH = H >> 1, PW = W >> 1;
    const int groups = Cout / GTOT;
    const int tid  = threadIdx.x;
    const int wv   = tid >> 6;                 // wave id
    const int lane = tid & 63;
    const int sw_  = wv % NSW;                 // spatial wave-tile id
    const int cg   = wv / NSW;                 // cin-group id

    const int bx      = blockIdx.x;
    const int tile_id = bx % ntiles;
    const int t1      = bx / ntiles;
    const int grp     = t1 % groups;
    const int n       = t1 / groups;
    const int c0      = grp * GTOT;
    const int cinbase = cg * CPG;
    // wave-uniform cin base -> uniform weight addresses -> SMEM s_load (lgkmcnt,
    // no vmcnt interaction with the staging DMAs, zero VGPR cost)
    const int cinbase_u = __builtin_amdgcn_readfirstlane(cinbase);

    const int td  = tile_id / nthw;
    const int rem = tile_id % nthw;
    const int th_ = rem / ntw;
    const int tw_ = rem % ntw;

    // spline prefix-coeff table (covered by the single initial barrier)
    for (int i = tid; i < GTOT * 11; i += TPB_) {
        const int gg  = i / 11;
        const int cnt = i % 11;
        const int c   = c0 + gg;
        float A = 0.f, B3 = 0.f, C3 = 0.f, Dd = 0.f;
        for (int j = 0; j < cnt; j++) {
            const float s = sw[c * 10 + j];
            const float k = knots[j];
            A  += s;
            B3 += 3.0f * s * k;
            C3 += 3.0f * s * k * k;
            Dd += s * k * k * k;
        }
        stbl[i] = make_float4(A, B3, C3, Dd);
    }

    // wave spatial origin (pooled coords)
    const int swd = sw_ / (BH * BW);
    const int r2  = sw_ % (BH * BW);
    const int swh = r2 / BW;
    const int sww = r2 % BW;
    const int pd0 = td  * (BD * WDT) + swd * WDT;
    const int ph0 = th_ * (BH * WHT) + swh * WHT;
    const int pw0 = tw_ * (BW * WWT) + sww * WWT;

    const int pwl = lane % WWT;
    const int phl = (lane / WWT) % WHT;
    const int pdl = lane / (WWT * WHT);

    const int d0 = 2 * pd0 - 1, h0 = 2 * ph0 - 1;
    const int w0 = 2 * pw0 - 1;
    const int wb = w0 & ~3;                    // 4-dword aligned chunk origin
    const int woff = w0 - wb;                  // 1 or 3

    // per-chunk global offsets + validity (per wave tile, same for all cins)
    int off[NCH];
    unsigned vm = 0;
#pragma unroll
    for (int k = 0; k < NCH; k++) {
        const int chunk = lane + 64 * k;
        const int row = chunk / CHK, cs = chunk - row * CHK;
        const int dz = row / IH, hy = row - dz * IH;
        const int dd = d0 + dz, hh = h0 + hy;
        const int wsd = wb + cs * 4;
        const bool ok = (chunk < CHUNKS) &
                        ((unsigned)dd < (unsigned)D) &
                        ((unsigned)hh < (unsigned)H) &
                        ((unsigned)wsd < (unsigned)W);
        off[k] = ok ? (dd * H + hh) * W + wsd : 0;
        vm |= (unsigned)ok << k;
    }

    const size_t chstride = (size_t)D * H * W;
    const float* xn = x + (size_t)n * CIN * chstride;

    float acc[G][8];
#pragma unroll
    for (int gg = 0; gg < G; gg++)
#pragma unroll
        for (int i = 0; i < 8; i++) acc[gg][i] = 0.0f;

    __syncthreads();   // stbl visible; vmcnt drained (clean slate)

    auto stage = [&](int ci, int buf) {
        const float* xc = xn + (size_t)ci * chstride;
        float* dst = &tile[wv][buf][0];
#pragma unroll
        for (int k = 0; k < NCH; k++) {
            const int chunk = lane + 64 * k;
            if ((k + 1) * 64 <= CHUNKS || chunk < CHUNKS) {
                const float* src = ((vm >> k) & 1) ? (xc + off[k]) : zbuf;
                async_ld16(src, dst + chunk * 4);
            }
        }
    };

    // epilogue for one 4-cout group: bias + spline(prefix-Horner) + SiLU + BN + maxpool
    const int pdg = pd0 + pdl, phg = ph0 + phl, pwg = pw0 + pwl;
    auto epilogue = [&](int gbase) {   // gbase = cout offset within block (cgo*G)
#pragma unroll
        for (int gg = 0; gg < G; gg++) {
            const int c = c0 + gbase + gg;
            const float bias = cb[c];
            const float W1 = w1[c], W2 = w2[c];
            const float scale = g[c] * rsqrtf(1.0f + 1e-5f);
            const float bb = beta[c];
            float m = -INFINITY;
#pragma unroll
            for (int i = 0; i < 8; i++) {
                const float y = acc[gg][i] + bias;
                int idx = (int)floorf((y + 1.0f) * 4.5f) + 1;
                idx = min(max(idx, 0), 10);
                const float4 cf = stbl[(gbase + gg) * 11 + idx];
                const float sp = ((cf.x * y - cf.y) * y + cf.z) * y - cf.w;
                const float silu = y / (1.0f + __expf(-y));
                const float o = fmaf(W1 * sp + W2 * silu, scale, bb);
                m = fmaxf(m, o);
            }
            out[((size_t)(n * Cout + c) * PD + pdg) * PH * PW + phg * PW + pwg] = m;
        }
    };

    // prologue: each wave stages its first cin into its buf 0
    stage(cinbase, 0);

#pragma unroll 1
    for (int s = 0; s < CPG; s++) {
        const int cur = s & (BUFS - 1);
        if (s + 1 < CPG) {
            stage(cinbase + s + 1, cur ^ 1);   // 6 DMA issues, stay in flight
            asm volatile("s_waitcnt vmcnt(6)" ::: "memory");  // cin s landed
        } else {
            asm volatile("s_waitcnt vmcnt(0)" ::: "memory");
        }

        const int ci_u = cinbase_u + s;        // wave-uniform weight row
        const float* tb = &tile[wv][cur][0];
        float r[64];
#pragma unroll
        for (int dz = 0; dz < 4; dz++)
#pragma unroll
        for (int dy = 0; dy < 4; dy++) {
            const int rb = ((2 * pdl + dz) * IH + (2 * phl + dy)) * PITCH +
                           woff + 2 * pwl;
            r[(dz * 4 + dy) * 4 + 0] = tb[rb + 0];
            r[(dz * 4 + dy) * 4 + 1] = tb[rb + 1];
            r[(dz * 4 + dy) * 4 + 2] = tb[rb + 2];
            r[(dz * 4 + dy) * 4 + 3] = tb[rb + 3];
        }

#pragma unroll 1
        for (int cgo = 0; cgo < CGO; cgo++) {
            if constexpr (CGO > 1) {           // fresh accumulators per cout-group
#pragma unroll
                for (int gg = 0; gg < G; gg++)
#pragma unroll
                    for (int i = 0; i < 8; i++) acc[gg][i] = 0.0f;
            }
            const int cbase = cgo * G;
#pragma unroll
            for (int gg = 0; gg < G; gg++) {
                // uniform address -> s_load (SMEM), separate lgkm counter
                const float4* wq = wpk +
                    ((size_t)(c0 + cbase + gg) * CIN + ci_u) * 7;
                float4 q[7];
#pragma unroll
                for (int ch = 0; ch < 7; ch++) q[ch] = wq[ch];
#pragma unroll
                for (int ch = 0; ch < 7; ch++) {
#pragma unroll
                    for (int j = 0; j < 4; j++) {
                        const int tap = ch * 4 + j;
                        if (tap < 27) {
                            const float wvj = (j == 0) ? q[ch].x
                                            : (j == 1) ? q[ch].y
                                            : (j == 2) ? q[ch].z : q[ch].w;
                            const int kd = tap / 9, kh = (tap % 9) / 3,
                                      kw = tap % 3;
#pragma unroll
                            for (int od = 0; od < 2; od++)
#pragma unroll
                            for (int oh = 0; oh < 2; oh++)
#pragma unroll
                            for (int ow = 0; ow < 2; ow++)
                                acc[gg][(od * 2 + oh) * 2 + ow] =
                                    fmaf(wvj,
                                         r[((od + kd) * 4 + (oh + kh)) * 4 + (ow + kw)],
                                         acc[gg][(od * 2 + oh) * 2 + ow]);
                        }
                    }
                }
            }
            if constexpr (CGO > 1) epilogue(cbase);   // CIN==1: done with this group
        }
    }

    if constexpr (CGO == 1) {
        // combine partial accumulators across cin-groups (scratch aliases tile).
        // scratch MUST be indexed by (cg, sw_) jointly (r14 replay race).
        float* af = &acc[0][0];
        if (CSPLIT > 1) {
            __syncthreads();                    // all waves done with their tiles
            float* scratch = &tile[0][0][0];
            if (cg > 0) {
#pragma unroll
                for (int idx = 0; idx < G * 8; idx++)
                    scratch[((idx * (CSPLIT - 1) + (cg - 1)) * NSW + sw_) * 64 + lane]
                        = af[idx];
            }
            __syncthreads();
            if (cg == 0) {
#pragma unroll
                for (int idx = 0; idx < G * 8; idx++) {
                    float s2 = af[idx];
                    for (int j = 0; j < CSPLIT - 1; j++)
                        s2 += scratch[((idx * (CSPLIT - 1) + j) * NSW + sw_) * 64 + lane];
                    af[idx] = s2;
                }
            }
        }
        if (cg == 0) epilogue(0);
    }
}

// Fused head: global mean pool (256 rows of 512) + fc1/relu + fc2. One block.
__global__ __launch_bounds__(256) void head_kernel(
    const float* __restrict__ h,    // [2*128][512] = h3
    const float* __restrict__ fw1, const float* __restrict__ fb1,
    const float* __restrict__ fw2, const float* __restrict__ fb2,
    float* __restrict__ out)        // [2][2]
{
    __shared__ float pooled[256];
    __shared__ float hbuf[2][256];
    const int tid = threadIdx.x, w = tid >> 6, lane = tid & 63;
    for (int p = w; p < 256; p += 4) {
        const float* row = h + (size_t)p * 512;
        float s = 0.0f;
#pragma unroll
        for (int i = 0; i < 8; i++) s += row[lane + 64 * i];
#pragma unroll
        for (int o = 32; o > 0; o >>= 1) s += __shfl_down(s, o, 64);
        if (lane == 0) pooled[p] = s * (1.0f / 512.0f);
    }
    __syncthreads();
    const int j = tid;
#pragma unroll
    for (int nn = 0; nn < 2; nn++) {
        float s = fb1[j];
        for (int k = 0; k < 128; k++)
            s = fmaf(pooled[nn * 128 + k], fw1[j * 128 + k], s);
        hbuf[nn][j] = fmaxf(s, 0.0f);
    }
    __syncthreads();
    const int wid = j >> 6, l2 = j & 63;
    const int nn = wid >> 1, oo = wid & 1;
    float s = 0.0f;
    for (int k = l2; k < 256; k += 64) s += hbuf[nn][k] * fw2[oo * 256 + k];
#pragma unroll
    for (int o = 32; o > 0; o >>= 1) s += __shfl_down(s, o, 64);
    if (l2 == 0) out[nn * 2 + oo] = s + fb2[oo];
}

extern "C" void kernel_launch(void* const* d_in, const int* in_sizes, int n_in,
                              void* d_out, int out_size, void* d_ws, size_t ws_size,
                              hipStream_t stream) {
    const float* x      = (const float*)d_in[0];
    const float* c1_w   = (const float*)d_in[1];
    const float* c1_b   = (const float*)d_in[2];
    const float* c1_kn  = (const float*)d_in[3];
    const float* c1_sw  = (const float*)d_in[4];
    const float* c1_w1  = (const float*)d_in[5];
    const float* c1_w2  = (const float*)d_in[6];
    const float* bn1_g  = (const float*)d_in[7];
    const float* bn1_b  = (const float*)d_in[8];
    const float* c2_w   = (const float*)d_in[9];
    const float* c2_b   = (const float*)d_in[10];
    const float* c2_kn  = (const float*)d_in[11];
    const float* c2_sw  = (const float*)d_in[12];
    const float* c2_w1  = (const float*)d_in[13];
    const float* c2_w2  = (const float*)d_in[14];
    const float* bn2_g  = (const float*)d_in[15];
    const float* bn2_b  = (const float*)d_in[16];
    const float* c3_w   = (const float*)d_in[17];
    const float* c3_b   = (const float*)d_in[18];
    const float* c3_kn  = (const float*)d_in[19];
    const float* c3_sw  = (const float*)d_in[20];
    const float* c3_w1  = (const float*)d_in[21];
    const float* c3_w2  = (const float*)d_in[22];
    const float* bn3_g  = (const float*)d_in[23];
    const float* bn3_b  = (const float*)d_in[24];
    const float* fc1_w  = (const float*)d_in[25];
    const float* fc1_b  = (const float*)d_in[26];
    const float* fc2_w  = (const float*)d_in[27];
    const float* fc2_b  = (const float*)d_in[28];

    float* ws = (float*)d_ws;
    float* h1     = ws;                  // 2*32*32^3 = 2,097,152 fl
    float* h2     = h1 + 2097152;        // 2*64*16^3 =   524,288 fl
    float* h3     = h2 + 524288;         // 2*128*8^3 =   131,072 fl
    float* pooled = h3 + 131072;         // 256 fl (unused, layout keep)
    float* zbuf   = pooled + 256;        // 64 B zeros (16B aligned)
    float* wp1    = zbuf + 16;           // 32*1*28   =       896 fl (16B aligned)
    float* wp2    = wp1 + 896;           // 64*32*28  =    57,344 fl
    float* wp3    = wp2 + 57344;         // 128*64*28 =   229,376 fl

    hipMemsetAsync(zbuf, 0, 64, stream);

    // pack all conv weights to pitch-28 (aligned float4 x7): 10272 (c,ci) pairs
    repack_kernel<<<dim3(41), dim3(256), 0, stream>>>(c1_w, c2_w, c3_w,
                                                      wp1, wp2, wp3);

    // All layers: wave tile 2x4x8 (ID=6, IH=10, PITCH=24, 6 DMA issues/cin).
    // L1: (2,1,64^3)->(2,32,32^3). 4 spatial waves (2x2x1), CGO=8: stage + r[]
    // once, 8 cout-groups (all 32 couts) per block. grid = 2*1*128 = 256 blocks
    // (1/CU, uniform). LDS ~28.7KB.
    spline_block_kernel<256, 1, 1, 4, 8, 2, 4, 8, 2, 2, 1>
        <<<dim3(256), dim3(256), 0, stream>>>(
        x, (const float4*)wp1, c1_b, c1_kn, c1_sw, c1_w1, c1_w2, bn1_g, bn1_b,
        zbuf, h1, 2, 32, 64, 64, 64, 128, 16, 4);
    // L2: (2,32,32^3)->(2,64,16^3). CSPLIT=2 x 2 spatial waves; scalar weights;
    // LDS ~47KB -> 2 blocks/CU; grid = 2*16*32 = 1024.
    spline_block_kernel<256, 32, 2, 4, 1, 2, 4, 8, 1, 1, 2>
        <<<dim3(1024), dim3(256), 0, stream>>>(
        h1, (const float4*)wp2, c2_b, c2_kn, c2_sw, c2_w1, c2_w2, bn2_g, bn2_b,
        zbuf, h2, 2, 64, 32, 32, 32, 32, 4, 1);
    // L3: (2,64,16^3)->(2,128,8^3). CSPLIT=4, scalar weights. grid = 2*32*8 = 512.
    spline_block_kernel<256, 64, 4, 4, 1, 2, 4, 8, 1, 1, 1>
        <<<dim3(512), dim3(256), 0, stream>>>(
        h2, (const float4*)wp3, c3_b, c3_kn, c3_sw, c3_w1, c3_w2, bn3_g, bn3_b,
        zbuf, h3, 2, 128, 16, 16, 16, 8, 2, 1);
    // fused head (mean pool + fc1 + fc2)
    head_kernel<<<dim3(1), dim3(256), 0, stream>>>(h3, fc1_w, fc1_b, fc2_w, fc2_b,
                                                   (float*)d_out);
}

// Round 7
// 349.012 us; speedup vs baseline: 1.0832x; 1.0815x over previous
//
#include <hip/hip_runtime.h>
#include <math.h>

// ConvKAN3D: 3x [conv3d(3x3x3,pad1) -> cubic KAN spline + SiLU -> BN(eval) -> maxpool 2x2x2]
// then global mean pool + fc1/relu/fc2.
// r17: r16 with the L1 occupancy error fixed.
//  - L1: CGO=2 @ grid 1024 (4 blocks/CU, 16 waves/CU). r16's CGO=8 @ grid 256 was
//    1 wave/SIMD -> every stall serialized -> L1 ~80us. r12's CGO=1 @ 2048 was
//    33.6us. CGO=2 keeps the stage-amortization (each tile staged 4x total instead
//    of 8x) at full occupancy.
//  - L2/L3 unchanged from r16 (measured: scalar s_load weights cut L2 126->122.3,
//    VGPR 92->76; vmcnt queue now contains only staging DMAs).
//  - zbuf zeroing folded into repack_kernel (r12/r16 showed ~90us of inter-kernel
//    gaps across 6 dispatches; one fewer dispatch).
// Measured-dead-ends (do not retry): padding/alignment of LDS reads (r15: the
// conflict counter is structural, unchanged at 1.049e7; dur worse), TPB=128 (r13),
// 1 block/CU geometries (r16-L1), G=8 with r[64] (r8 spill), cin-split via global
// atomics (r5). launch_bounds stays (TPB,2). CSPLIT scratch indexed by (cg,sw_)
// jointly (r14 replay race).

#define GLOBAL_AS __attribute__((address_space(1)))
#define LDS_AS    __attribute__((address_space(3)))

static __device__ __forceinline__ void async_ld16(const float* g, float* l) {
    __builtin_amdgcn_global_load_lds((const GLOBAL_AS void*)g, (LDS_AS void*)l,
                                     16, 0, 0);
}

// Pack [C][CIN][27] conv weights -> [C*CIN][28] (16B-aligned float4 x 7, tail 0).
// Tail threads also zero zbuf (removes the separate memset dispatch).
__global__ __launch_bounds__(256) void repack_kernel(
    const float* __restrict__ w1, const float* __restrict__ w2,
    const float* __restrict__ w3,
    float* __restrict__ o1, float* __restrict__ o2, float* __restrict__ o3,
    float* __restrict__ zbuf)
{
    const int i = blockIdx.x * 256 + threadIdx.x;   // (c,ci) pair id
    const float* src;
    float* dst;
    if (i < 32)            { src = w1 + i * 27;           dst = o1 + i * 28; }
    else if (i < 2080)     { const int j = i - 32;   src = w2 + j * 27; dst = o2 + j * 28; }
    else if (i < 10272)    { const int j = i - 2080; src = w3 + j * 27; dst = o3 + j * 28; }
    else { if (i < 10288) zbuf[i - 10272] = 0.0f; return; }
#pragma unroll
    for (int t = 0; t < 27; t++) dst[t] = src[t];
    dst[27] = 0.0f;
}

template <int TPB_, int CIN, int CSPLIT, int G, int CGO,
          int WDT, int WHT, int WWT, int BD, int BH, int BW>
__global__ __launch_bounds__(TPB_, 2) void spline_block_kernel(
    const float* __restrict__ x,    // [N, CIN, D, H, W]
    const float4* __restrict__ wpk, // [Cout*CIN][7] packed conv weights
    const float* __restrict__ cb,   // [Cout]
    const float* __restrict__ knots,// [10]
    const float* __restrict__ sw,   // [Cout, 10]
    const float* __restrict__ w1,
    const float* __restrict__ w2,
    const float* __restrict__ g,
    const float* __restrict__ beta,
    const float* __restrict__ zbuf, // >=64B of zeros (16B aligned)
    float* __restrict__ out,        // [N, Cout, D/2, H/2, W/2]
    int N, int Cout, int D, int H, int W,
    int ntiles, int nthw, int ntw)
{
    constexpr int GTOT   = G * CGO;            // couts per block
    constexpr int NSW    = BD * BH * BW;       // spatial wave-tiles per block
    constexpr int NW     = TPB_ / 64;          // waves per block
    constexpr int CPG    = CIN / CSPLIT;       // cins per cin-group
    constexpr int ID     = 2 * WDT + 2;        // input planes (d) per wave tile
    constexpr int IH     = 2 * WHT + 2;        // input rows (h) per wave tile
    constexpr int CHK    = (WWT + 4) / 2;      // 16B chunks per input row
    constexpr int PITCH  = CHK * 4;            // dwords per row
    constexpr int ROWS   = ID * IH;
    constexpr int CHUNKS = ROWS * CHK;
    constexpr int PHYS   = CHUNKS * 4;         // dwords per wave buffer
    constexpr int NCH    = (CHUNKS + 63) / 64; // DMA issues per cin per lane
    constexpr int BUFS   = (CPG > 1) ? 2 : 1;
    static_assert(NW == NSW * CSPLIT, "waves = spatial-tiles x cin-split");
    static_assert(WDT * WHT * WWT == 64, "one wave per spatial tile");
    static_assert(CIN % CSPLIT == 0, "cin divisible");
    static_assert(G == 4, "acc layout assumes G==4");
    static_assert(CGO == 1 || (CSPLIT == 1 && CIN == 1),
                  "multi-cout-group only for the CIN=1 single-step layer");
    static_assert(NCH <= 32, "mask fits u32");
    static_assert(NCH == 6, "s_waitcnt vmcnt(6) literal assumes 6 issues/cin");
    static_assert(CSPLIT == 1 ||
                  (CSPLIT - 1) * NSW * 64 * G * 8 <= NW * BUFS * PHYS,
                  "reduction scratch fits in tile");

    __shared__ __align__(16) float tile[NW][BUFS][PHYS];
    __shared__ float4 stbl[GTOT * 11];         // spline prefix coeffs {A,3B,3C,D}

    const int PD = D >> 1, PH = H >> 1, PW = W >> 1;
    const int groups = Cout / GTOT;
    const int tid  = threadIdx.x;
    const int wv   = tid >> 6;                 // wave id
    const int lane = tid & 63;
    const int sw_  = wv % NSW;                 // spatial wave-tile id
    const int cg   = wv / NSW;                 // cin-group id

    const int bx      = blockIdx.x;
    const int tile_id = bx % ntiles;
    const int t1      = bx / ntiles;
    const int grp     = t1 % groups;
    const int n       = t1 / groups;
    const int c0      = grp * GTOT;
    const int cinbase = cg * CPG;
    // wave-uniform cin base -> uniform weight addresses -> SMEM s_load (lgkmcnt,
    // no vmcnt interaction with the staging DMAs, zero VGPR cost)
    const int cinbase_u = __builtin_amdgcn_readfirstlane(cinbase);

    const int td  = tile_id / nthw;
    const int rem = tile_id % nthw;
    const int th_ = rem / ntw;
    const int tw_ = rem % ntw;

    // spline prefix-coeff table (covered by the single initial barrier)
    for (int i = tid; i < GTOT * 11; i += TPB_) {
        const int gg  = i / 11;
        const int cnt = i % 11;
        const int c   = c0 + gg;
        float A = 0.f, B3 = 0.f, C3 = 0.f, Dd = 0.f;
        for (int j = 0; j < cnt; j++) {
            const float s = sw[c * 10 + j];
            const float k = knots[j];
            A  += s;
            B3 += 3.0f * s * k;
            C3 += 3.0f * s * k * k;
            Dd += s * k * k * k;
        }
        stbl[i] = make_float4(A, B3, C3, Dd);
    }

    // wave spatial origin (pooled coords)
    const int swd = sw_ / (BH * BW);
    const int r2  = sw_ % (BH * BW);
    const int swh = r2 / BW;
    const int sww = r2 % BW;
    const int pd0 = td  * (BD * WDT) + swd * WDT;
    const int ph0 = th_ * (BH * WHT) + swh * WHT;
    const int pw0 = tw_ * (BW * WWT) + sww * WWT;

    const int pwl = lane % WWT;
    const int phl = (lane / WWT) % WHT;
    const int pdl = lane / (WWT * WHT);

    const int d0 = 2 * pd0 - 1, h0 = 2 * ph0 - 1;
    const int w0 = 2 * pw0 - 1;
    const int wb = w0 & ~3;                    // 4-dword aligned chunk origin
    const int woff = w0 - wb;                  // 1 or 3

    // per-chunk global offsets + validity (per wave tile, same for all cins)
    int off[NCH];
    unsigned vm = 0;
#pragma unroll
    for (int k = 0; k < NCH; k++) {
        const int chunk = lane + 64 * k;
        const int row = chunk / CHK, cs = chunk - row * CHK;
        const int dz = row / IH, hy = row - dz * IH;
        const int dd = d0 + dz, hh = h0 + hy;
        const int wsd = wb + cs * 4;
        const bool ok = (chunk < CHUNKS) &
                        ((unsigned)dd < (unsigned)D) &
                        ((unsigned)hh < (unsigned)H) &
                        ((unsigned)wsd < (unsigned)W);
        off[k] = ok ? (dd * H + hh) * W + wsd : 0;
        vm |= (unsigned)ok << k;
    }

    const size_t chstride = (size_t)D * H * W;
    const float* xn = x + (size_t)n * CIN * chstride;

    float acc[G][8];
#pragma unroll
    for (int gg = 0; gg < G; gg++)
#pragma unroll
        for (int i = 0; i < 8; i++) acc[gg][i] = 0.0f;

    __syncthreads();   // stbl visible; vmcnt drained (clean slate)

    auto stage = [&](int ci, int buf) {
        const float* xc = xn + (size_t)ci * chstride;
        float* dst = &tile[wv][buf][0];
#pragma unroll
        for (int k = 0; k < NCH; k++) {
            const int chunk = lane + 64 * k;
            if ((k + 1) * 64 <= CHUNKS || chunk < CHUNKS) {
                const float* src = ((vm >> k) & 1) ? (xc + off[k]) : zbuf;
                async_ld16(src, dst + chunk * 4);
            }
        }
    };

    // epilogue for one 4-cout group: bias + spline(prefix-Horner) + SiLU + BN + maxpool
    const int pdg = pd0 + pdl, phg = ph0 + phl, pwg = pw0 + pwl;
    auto epilogue = [&](int gbase) {   // gbase = cout offset within block (cgo*G)
#pragma unroll
        for (int gg = 0; gg < G; gg++) {
            const int c = c0 + gbase + gg;
            const float bias = cb[c];
            const float W1 = w1[c], W2 = w2[c];
            const float scale = g[c] * rsqrtf(1.0f + 1e-5f);
            const float bb = beta[c];
            float m = -INFINITY;
#pragma unroll
            for (int i = 0; i < 8; i++) {
                const float y = acc[gg][i] + bias;
                int idx = (int)floorf((y + 1.0f) * 4.5f) + 1;
                idx = min(max(idx, 0), 10);
                const float4 cf = stbl[(gbase + gg) * 11 + idx];
                const float sp = ((cf.x * y - cf.y) * y + cf.z) * y - cf.w;
                const float silu = y / (1.0f + __expf(-y));
                const float o = fmaf(W1 * sp + W2 * silu, scale, bb);
                m = fmaxf(m, o);
            }
            out[((size_t)(n * Cout + c) * PD + pdg) * PH * PW + phg * PW + pwg] = m;
        }
    };

    // prologue: each wave stages its first cin into its buf 0
    stage(cinbase, 0);

#pragma unroll 1
    for (int s = 0; s < CPG; s++) {
        const int cur = s & (BUFS - 1);
        if (s + 1 < CPG) {
            stage(cinbase + s + 1, cur ^ 1);   // 6 DMA issues, stay in flight
            asm volatile("s_waitcnt vmcnt(6)" ::: "memory");  // cin s landed
        } else {
            asm volatile("s_waitcnt vmcnt(0)" ::: "memory");
        }

        const int ci_u = cinbase_u + s;        // wave-uniform weight row
        const float* tb = &tile[wv][cur][0];
        float r[64];
#pragma unroll
        for (int dz = 0; dz < 4; dz++)
#pragma unroll
        for (int dy = 0; dy < 4; dy++) {
            const int rb = ((2 * pdl + dz) * IH + (2 * phl + dy)) * PITCH +
                           woff + 2 * pwl;
            r[(dz * 4 + dy) * 4 + 0] = tb[rb + 0];
            r[(dz * 4 + dy) * 4 + 1] = tb[rb + 1];
            r[(dz * 4 + dy) * 4 + 2] = tb[rb + 2];
            r[(dz * 4 + dy) * 4 + 3] = tb[rb + 3];
        }

#pragma unroll 1
        for (int cgo = 0; cgo < CGO; cgo++) {
            if constexpr (CGO > 1) {           // fresh accumulators per cout-group
#pragma unroll
                for (int gg = 0; gg < G; gg++)
#pragma unroll
                    for (int i = 0; i < 8; i++) acc[gg][i] = 0.0f;
            }
            const int cbase = cgo * G;
#pragma unroll
            for (int gg = 0; gg < G; gg++) {
                // uniform address -> s_load (SMEM), separate lgkm counter
                const float4* wq = wpk +
                    ((size_t)(c0 + cbase + gg) * CIN + ci_u) * 7;
                float4 q[7];
#pragma unroll
                for (int ch = 0; ch < 7; ch++) q[ch] = wq[ch];
#pragma unroll
                for (int ch = 0; ch < 7; ch++) {
#pragma unroll
                    for (int j = 0; j < 4; j++) {
                        const int tap = ch * 4 + j;
                        if (tap < 27) {
                            const float wvj = (j == 0) ? q[ch].x
                                            : (j == 1) ? q[ch].y
                                            : (j == 2) ? q[ch].z : q[ch].w;
                            const int kd = tap / 9, kh = (tap % 9) / 3,
                                      kw = tap % 3;
#pragma unroll
                            for (int od = 0; od < 2; od++)
#pragma unroll
                            for (int oh = 0; oh < 2; oh++)
#pragma unroll
                            for (int ow = 0; ow < 2; ow++)
                                acc[gg][(od * 2 + oh) * 2 + ow] =
                                    fmaf(wvj,
                                         r[((od + kd) * 4 + (oh + kh)) * 4 + (ow + kw)],
                                         acc[gg][(od * 2 + oh) * 2 + ow]);
                        }
                    }
                }
            }
            if constexpr (CGO > 1) epilogue(cbase);   // CIN==1: done with this group
        }
    }

    if constexpr (CGO == 1) {
        // combine partial accumulators across cin-groups (scratch aliases tile).
        // scratch MUST be indexed by (cg, sw_) jointly (r14 replay race).
        float* af = &acc[0][0];
        if (CSPLIT > 1) {
            __syncthreads();                    // all waves done with their tiles
            float* scratch = &tile[0][0][0];
            if (cg > 0) {
#pragma unroll
                for (int idx = 0; idx < G * 8; idx++)
                    scratch[((idx * (CSPLIT - 1) + (cg - 1)) * NSW + sw_) * 64 + lane]
                        = af[idx];
            }
            __syncthreads();
            if (cg == 0) {
#pragma unroll
                for (int idx = 0; idx < G * 8; idx++) {
                    float s2 = af[idx];
                    for (int j = 0; j < CSPLIT - 1; j++)
                        s2 += scratch[((idx * (CSPLIT - 1) + j) * NSW + sw_) * 64 + lane];
                    af[idx] = s2;
                }
            }
        }
        if (cg == 0) epilogue(0);
    }
}

// Fused head: global mean pool (256 rows of 512) + fc1/relu + fc2. One block.
__global__ __launch_bounds__(256) void head_kernel(
    const float* __restrict__ h,    // [2*128][512] = h3
    const float* __restrict__ fw1, const float* __restrict__ fb1,
    const float* __restrict__ fw2, const float* __restrict__ fb2,
    float* __restrict__ out)        // [2][2]
{
    __shared__ float pooled[256];
    __shared__ float hbuf[2][256];
    const int tid = threadIdx.x, w = tid >> 6, lane = tid & 63;
    for (int p = w; p < 256; p += 4) {
        const float* row = h + (size_t)p * 512;
        float s = 0.0f;
#pragma unroll
        for (int i = 0; i < 8; i++) s += row[lane + 64 * i];
#pragma unroll
        for (int o = 32; o > 0; o >>= 1) s += __shfl_down(s, o, 64);
        if (lane == 0) pooled[p] = s * (1.0f / 512.0f);
    }
    __syncthreads();
    const int j = tid;
#pragma unroll
    for (int nn = 0; nn < 2; nn++) {
        float s = fb1[j];
        for (int k = 0; k < 128; k++)
            s = fmaf(pooled[nn * 128 + k], fw1[j * 128 + k], s);
        hbuf[nn][j] = fmaxf(s, 0.0f);
    }
    __syncthreads();
    const int wid = j >> 6, l2 = j & 63;
    const int nn = wid >> 1, oo = wid & 1;
    float s = 0.0f;
    for (int k = l2; k < 256; k += 64) s += hbuf[nn][k] * fw2[oo * 256 + k];
#pragma unroll
    for (int o = 32; o > 0; o >>= 1) s += __shfl_down(s, o, 64);
    if (l2 == 0) out[nn * 2 + oo] = s + fb2[oo];
}

extern "C" void kernel_launch(void* const* d_in, const int* in_sizes, int n_in,
                              void* d_out, int out_size, void* d_ws, size_t ws_size,
                              hipStream_t stream) {
    const float* x      = (const float*)d_in[0];
    const float* c1_w   = (const float*)d_in[1];
    const float* c1_b   = (const float*)d_in[2];
    const float* c1_kn  = (const float*)d_in[3];
    const float* c1_sw  = (const float*)d_in[4];
    const float* c1_w1  = (const float*)d_in[5];
    const float* c1_w2  = (const float*)d_in[6];
    const float* bn1_g  = (const float*)d_in[7];
    const float* bn1_b  = (const float*)d_in[8];
    const float* c2_w   = (const float*)d_in[9];
    const float* c2_b   = (const float*)d_in[10];
    const float* c2_kn  = (const float*)d_in[11];
    const float* c2_sw  = (const float*)d_in[12];
    const float* c2_w1  = (const float*)d_in[13];
    const float* c2_w2  = (const float*)d_in[14];
    const float* bn2_g  = (const float*)d_in[15];
    const float* bn2_b  = (const float*)d_in[16];
    const float* c3_w   = (const float*)d_in[17];
    const float* c3_b   = (const float*)d_in[18];
    const float* c3_kn  = (const float*)d_in[19];
    const float* c3_sw  = (const float*)d_in[20];
    const float* c3_w1  = (const float*)d_in[21];
    const float* c3_w2  = (const float*)d_in[22];
    const float* bn3_g  = (const float*)d_in[23];
    const float* bn3_b  = (const float*)d_in[24];
    const float* fc1_w  = (const float*)d_in[25];
    const float* fc1_b  = (const float*)d_in[26];
    const float* fc2_w  = (const float*)d_in[27];
    const float* fc2_b  = (const float*)d_in[28];

    float* ws = (float*)d_ws;
    float* h1     = ws;                  // 2*32*32^3 = 2,097,152 fl
    float* h2     = h1 + 2097152;        // 2*64*16^3 =   524,288 fl
    float* h3     = h2 + 524288;         // 2*128*8^3 =   131,072 fl
    float* pooled = h3 + 131072;         // 256 fl (unused, layout keep)
    float* zbuf   = pooled + 256;        // 64 B zeros (16B aligned)
    float* wp1    = zbuf + 16;           // 32*1*28   =       896 fl (16B aligned)
    float* wp2    = wp1 + 896;           // 64*32*28  =    57,344 fl
    float* wp3    = wp2 + 57344;         // 128*64*28 =   229,376 fl

    // pack all conv weights to pitch-28 (aligned float4 x7) + zero zbuf
    repack_kernel<<<dim3(41), dim3(256), 0, stream>>>(c1_w, c2_w, c3_w,
                                                      wp1, wp2, wp3, zbuf);

    // All layers: wave tile 2x4x8 (ID=6, IH=10, PITCH=24, 6 DMA issues/cin).
    // L1: (2,1,64^3)->(2,32,32^3). 4 spatial waves (2x2x1), CGO=2: stage + r[]
    // once, 2 cout-groups (8 couts) per block. grid = 2*4*128 = 1024 blocks =
    // exactly 4/CU (16 waves/CU). LDS ~24.4KB.
    spline_block_kernel<256, 1, 1, 4, 2, 2, 4, 8, 2, 2, 1>
        <<<dim3(1024), dim3(256), 0, stream>>>(
        x, (const float4*)wp1, c1_b, c1_kn, c1_sw, c1_w1, c1_w2, bn1_g, bn1_b,
        zbuf, h1, 2, 32, 64, 64, 64, 128, 16, 4);
    // L2: (2,32,32^3)->(2,64,16^3). CSPLIT=2 x 2 spatial waves; scalar weights;
    // LDS ~47KB; grid = 2*16*32 = 1024. (r16 measured 122.3us)
    spline_block_kernel<256, 32, 2, 4, 1, 2, 4, 8, 1, 1, 2>
        <<<dim3(1024), dim3(256), 0, stream>>>(
        h1, (const float4*)wp2, c2_b, c2_kn, c2_sw, c2_w1, c2_w2, bn2_g, bn2_b,
        zbuf, h2, 2, 64, 32, 32, 32, 32, 4, 1);
    // L3: (2,64,16^3)->(2,128,8^3). CSPLIT=4, scalar weights. grid = 2*32*8 = 512.
    spline_block_kernel<256, 64, 4, 4, 1, 2, 4, 8, 1, 1, 1>
        <<<dim3(512), dim3(256), 0, stream>>>(
        h2, (const float4*)wp3, c3_b, c3_kn, c3_sw, c3_w1, c3_w2, bn3_g, bn3_b,
        zbuf, h3, 2, 128, 16, 16, 16, 8, 2, 1);
    // fused head (mean pool + fc1 + fc2)
    head_kernel<<<dim3(1), dim3(256), 0, stream>>>(h3, fc1_w, fc1_b, fc2_w, fc2_b,
                                                   (float*)d_out);
}